// Round 2
// baseline (3693.649 us; speedup 1.0000x reference)
//
#include <hip/hip_runtime.h>
#include <hip/hip_bf16.h>
#include <math.h>

#define DIM      512
#define D_STATE  16
#define D_CONV   4
#define D_INNER  1024
#define DT_RANK  32
#define B_SZ     2
#define SEQ      2048
#define NTOK     (B_SZ * SEQ)   // 4096

// ---------------- GEMM: C[M,N] = alpha * A[M,K] @ W[N,K]^T (+=C if accum) ----
// A row-major [M,lda], W row-major [N,ldw], C row-major [M,ldc].
// Requires M%64==0, N%64==0, K%16==0, lda%4==0, ldw%4==0, k-start 16-aligned.
#define GBM 64
#define GBN 64
#define GBK 16

__global__ __launch_bounds__(256)
void gemm_xwT(const float* __restrict__ A, int lda,
              const float* __restrict__ W, int ldw,
              float* __restrict__ C, int ldc,
              int M, int N, int K, float alpha, int accum)
{
    __shared__ float As[GBK][GBM + 4];
    __shared__ float Ws[GBK][GBN + 4];

    const int tid = threadIdx.x;
    const int tx = tid & 15;        // 0..15  -> n sub-tile
    const int ty = tid >> 4;        // 0..15  -> m sub-tile
    const int m0 = blockIdx.y * GBM;
    const int n0 = blockIdx.x * GBN;

    // loader mapping: each thread loads one float4 along k
    const int li = tid >> 2;          // 0..63 (row within tile)
    const int lj = (tid & 3) * 4;     // 0,4,8,12 (k within tile)

    float acc[4][4];
#pragma unroll
    for (int i = 0; i < 4; ++i)
#pragma unroll
        for (int j = 0; j < 4; ++j) acc[i][j] = 0.f;

    for (int k0 = 0; k0 < K; k0 += GBK) {
        float4 av = *(const float4*)&A[(m0 + li) * lda + k0 + lj];
        float4 wv = *(const float4*)&W[(n0 + li) * ldw + k0 + lj];
        As[lj + 0][li] = av.x; As[lj + 1][li] = av.y;
        As[lj + 2][li] = av.z; As[lj + 3][li] = av.w;
        Ws[lj + 0][li] = wv.x; Ws[lj + 1][li] = wv.y;
        Ws[lj + 2][li] = wv.z; Ws[lj + 3][li] = wv.w;
        __syncthreads();

#pragma unroll
        for (int kk = 0; kk < GBK; ++kk) {
            float4 a = *(const float4*)&As[kk][ty * 4];
            float4 b = *(const float4*)&Ws[kk][tx * 4];
            float ar[4] = {a.x, a.y, a.z, a.w};
            float br[4] = {b.x, b.y, b.z, b.w};
#pragma unroll
            for (int i = 0; i < 4; ++i)
#pragma unroll
                for (int j = 0; j < 4; ++j)
                    acc[i][j] = fmaf(ar[i], br[j], acc[i][j]);
        }
        __syncthreads();
    }

#pragma unroll
    for (int i = 0; i < 4; ++i) {
        int m = m0 + ty * 4 + i;
#pragma unroll
        for (int j = 0; j < 4; ++j) {
            int n = n0 + tx * 4 + j;
            float v = alpha * acc[i][j];
            if (accum) C[m * ldc + n] += v;
            else       C[m * ldc + n] = v;
        }
    }
}

// ---------------- depthwise causal conv (k=4) + bias + SiLU --------------
// xz: [NTOK, 2*D_INNER] ; xi = cols [0, D_INNER). Writes xc [NTOK, D_INNER].
// rev=0: xc[u] = b + sum_k w[k]*xi[u-3+k]   (causal)
// rev=1: xc[u] = b + sum_k w[k]*xi[u+3-k]   (anticausal, flipped taps)
__global__ __launch_bounds__(256)
void conv_silu_kernel(const float* __restrict__ xz,
                      const float* __restrict__ cw,   // [D_INNER, 4]
                      const float* __restrict__ cb,   // [D_INNER]
                      float* __restrict__ xc, int rev)
{
    int idx = blockIdx.x * 256 + threadIdx.x;
    if (idx >= NTOK * D_INNER) return;
    int c   = idx & (D_INNER - 1);
    int row = idx >> 10;
    int b   = row / SEQ;
    int u   = row - b * SEQ;

    float w0 = cw[c * 4 + 0], w1 = cw[c * 4 + 1];
    float w2 = cw[c * 4 + 2], w3 = cw[c * 4 + 3];
    float accv = cb[c];
    if (!rev) {
#pragma unroll
        for (int k = 0; k < 4; ++k) {
            int uu = u - 3 + k;
            float wv = (k == 0) ? w0 : (k == 1) ? w1 : (k == 2) ? w2 : w3;
            if (uu >= 0)
                accv = fmaf(wv, xz[(b * SEQ + uu) * (2 * D_INNER) + c], accv);
        }
    } else {
#pragma unroll
        for (int k = 0; k < 4; ++k) {
            int uu = u + 3 - k;
            float wv = (k == 0) ? w0 : (k == 1) ? w1 : (k == 2) ? w2 : w3;
            if (uu < SEQ)
                accv = fmaf(wv, xz[(b * SEQ + uu) * (2 * D_INNER) + c], accv);
        }
    }
    // SiLU
    xc[idx] = accv / (1.f + expf(-accv));
}

// ---------------- dt bias + softplus (in place) --------------------------
__global__ __launch_bounds__(256)
void bias_softplus_kernel(float* __restrict__ dt, const float* __restrict__ dtb)
{
    int idx = blockIdx.x * 256 + threadIdx.x;
    if (idx >= NTOK * D_INNER) return;
    int c = idx & (D_INNER - 1);
    float v = dt[idx] + dtb[c];
    dt[idx] = (v > 20.f) ? v : log1pf(expf(v));
}

// ---------------- SSM scan ------------------------------------------------
// lane layout: state s = tid&15, local channel = tid>>4 (16 channels/block)
// ybar[row,c] = (sum_s h*C + D[c]*xc) * silu(z)
__global__ __launch_bounds__(256)
void scan_kernel(const float* __restrict__ dt,    // [NTOK, D_INNER]
                 const float* __restrict__ xc,    // [NTOK, D_INNER]
                 const float* __restrict__ xz,    // [NTOK, 2*D_INNER] (z at +D_INNER)
                 const float* __restrict__ xdbl,  // [NTOK, 64] (B at 32, C at 48)
                 const float* __restrict__ A_log, // [D_INNER, 16]
                 const float* __restrict__ Dp,    // [D_INNER]
                 float* __restrict__ ybar,        // [NTOK, D_INNER]
                 int rev)
{
    const int tid = threadIdx.x;
    const int s  = tid & 15;
    const int cl = tid >> 4;                 // 0..15
    const int b    = blockIdx.x >> 6;        // / (D_INNER/16)
    const int cblk = blockIdx.x & 63;
    const int c = cblk * 16 + cl;

    const float Acs = -expf(A_log[c * 16 + s]);
    const float Dc  = Dp[c];

    float h = 0.f;
    for (int t = 0; t < SEQ; ++t) {
        int u = rev ? (SEQ - 1 - t) : t;
        int row = b * SEQ + u;
        float dtv = dt[row * D_INNER + c];
        float xcv = xc[row * D_INNER + c];
        float Bv  = xdbl[row * 64 + 32 + s];
        float Cv  = xdbl[row * 64 + 48 + s];
        float da  = __expf(dtv * Acs);
        h = fmaf(da, h, dtv * xcv * Bv);
        float p = h * Cv;
        p += __shfl_xor(p, 1);
        p += __shfl_xor(p, 2);
        p += __shfl_xor(p, 4);
        p += __shfl_xor(p, 8);
        if (s == 0) {
            float zv = xz[row * (2 * D_INNER) + D_INNER + c];
            float y  = p + Dc * xcv;
            ybar[row * D_INNER + c] = y * (zv / (1.f + expf(-zv)));
        }
    }
}

extern "C" void kernel_launch(void* const* d_in, const int* in_sizes, int n_in,
                              void* d_out, int out_size, void* d_ws, size_t ws_size,
                              hipStream_t stream)
{
    const float* x = (const float*)d_in[0];
    float* out = (float*)d_out;
    float* ws  = (float*)d_ws;

    // workspace layout (floats), reused across directions:
    float* xz   = ws;                            // NTOK*2048
    float* xc   = xz   + (size_t)NTOK * 2 * D_INNER;   // NTOK*1024
    float* xdbl = xc   + (size_t)NTOK * D_INNER;       // NTOK*64
    float* dt   = xdbl + (size_t)NTOK * 64;            // NTOK*1024
    float* ybar = dt   + (size_t)NTOK * D_INNER;       // NTOK*1024

    const int elemN = NTOK * D_INNER;
    const int gElem = (elemN + 255) / 256;

    for (int dir = 0; dir < 2; ++dir) {
        const float* in_w    = (const float*)d_in[1 + dir * 9 + 0];
        const float* conv_w  = (const float*)d_in[1 + dir * 9 + 1];
        const float* conv_b  = (const float*)d_in[1 + dir * 9 + 2];
        const float* xproj_w = (const float*)d_in[1 + dir * 9 + 3];
        const float* dt_w    = (const float*)d_in[1 + dir * 9 + 4];
        const float* dt_b    = (const float*)d_in[1 + dir * 9 + 5];
        const float* A_log   = (const float*)d_in[1 + dir * 9 + 6];
        const float* Dp      = (const float*)d_in[1 + dir * 9 + 7];
        const float* out_w   = (const float*)d_in[1 + dir * 9 + 8];

        // 1) xz = x @ in_w.T   [4096, 2048]
        {
            dim3 g(2 * D_INNER / GBN, NTOK / GBM);
            gemm_xwT<<<g, 256, 0, stream>>>(x, DIM, in_w, DIM,
                                            xz, 2 * D_INNER,
                                            NTOK, 2 * D_INNER, DIM, 1.f, 0);
        }
        // 2) conv + silu -> xc
        conv_silu_kernel<<<gElem, 256, 0, stream>>>(xz, conv_w, conv_b, xc, dir);
        // 3) x_dbl = xc @ xproj_w.T   [4096, 64]
        {
            dim3 g(64 / GBN, NTOK / GBM);
            gemm_xwT<<<g, 256, 0, stream>>>(xc, D_INNER, xproj_w, D_INNER,
                                            xdbl, 64,
                                            NTOK, 64, D_INNER, 1.f, 0);
        }
        // 4) dt_pre = x_dbl[:, :32] @ dt_w.T   [4096, 1024]
        {
            dim3 g(D_INNER / GBN, NTOK / GBM);
            gemm_xwT<<<g, 256, 0, stream>>>(xdbl, 64, dt_w, DT_RANK,
                                            dt, D_INNER,
                                            NTOK, D_INNER, DT_RANK, 1.f, 0);
        }
        // 5) dt = softplus(dt_pre + dt_b)
        bias_softplus_kernel<<<gElem, 256, 0, stream>>>(dt, dt_b);
        // 6) scan -> ybar
        scan_kernel<<<B_SZ * (D_INNER / 16), 256, 0, stream>>>(
            dt, xc, xz, xdbl, A_log, Dp, ybar, dir);
        // 7) out (+)= 0.5 * ybar @ out_w.T   [4096, 512]
        {
            dim3 g(DIM / GBN, NTOK / GBM);
            gemm_xwT<<<g, 256, 0, stream>>>(ybar, D_INNER, out_w, D_INNER,
                                            out, DIM,
                                            NTOK, DIM, D_INNER, 0.5f, dir);
        }
    }
}

// Round 3
// 878.957 us; speedup vs baseline: 4.2023x; 4.2023x over previous
//
#include <hip/hip_runtime.h>
#include <hip/hip_bf16.h>
#include <math.h>

#define DIM      512
#define D_STATE  16
#define D_CONV   4
#define D_INNER  1024
#define DT_RANK  32
#define B_SZ     2
#define SEQ      2048
#define NTOK     (B_SZ * SEQ)   // 4096
#define CHUNK    128
#define NCH      (SEQ / CHUNK)  // 16

// ---------------- GEMM: C[M,N] = alpha * A[M,K] @ W[N,K]^T (+=C if accum) ----
#define GBM 64
#define GBN 64
#define GBK 16

__global__ __launch_bounds__(256)
void gemm_xwT(const float* __restrict__ A, int lda,
              const float* __restrict__ W, int ldw,
              float* __restrict__ C, int ldc,
              int M, int N, int K, float alpha, int accum)
{
    __shared__ float As[GBK][GBM + 4];
    __shared__ float Ws[GBK][GBN + 4];

    const int tid = threadIdx.x;
    const int tx = tid & 15;
    const int ty = tid >> 4;
    const int m0 = blockIdx.y * GBM;
    const int n0 = blockIdx.x * GBN;

    const int li = tid >> 2;
    const int lj = (tid & 3) * 4;

    float acc[4][4];
#pragma unroll
    for (int i = 0; i < 4; ++i)
#pragma unroll
        for (int j = 0; j < 4; ++j) acc[i][j] = 0.f;

    for (int k0 = 0; k0 < K; k0 += GBK) {
        float4 av = *(const float4*)&A[(m0 + li) * lda + k0 + lj];
        float4 wv = *(const float4*)&W[(n0 + li) * ldw + k0 + lj];
        As[lj + 0][li] = av.x; As[lj + 1][li] = av.y;
        As[lj + 2][li] = av.z; As[lj + 3][li] = av.w;
        Ws[lj + 0][li] = wv.x; Ws[lj + 1][li] = wv.y;
        Ws[lj + 2][li] = wv.z; Ws[lj + 3][li] = wv.w;
        __syncthreads();

#pragma unroll
        for (int kk = 0; kk < GBK; ++kk) {
            float4 a = *(const float4*)&As[kk][ty * 4];
            float4 b = *(const float4*)&Ws[kk][tx * 4];
            float ar[4] = {a.x, a.y, a.z, a.w};
            float br[4] = {b.x, b.y, b.z, b.w};
#pragma unroll
            for (int i = 0; i < 4; ++i)
#pragma unroll
                for (int j = 0; j < 4; ++j)
                    acc[i][j] = fmaf(ar[i], br[j], acc[i][j]);
        }
        __syncthreads();
    }

#pragma unroll
    for (int i = 0; i < 4; ++i) {
        int m = m0 + ty * 4 + i;
#pragma unroll
        for (int j = 0; j < 4; ++j) {
            int n = n0 + tx * 4 + j;
            float v = alpha * acc[i][j];
            if (accum) C[m * ldc + n] += v;
            else       C[m * ldc + n] = v;
        }
    }
}

// ---------------- depthwise causal conv (k=4) + bias + SiLU --------------
__global__ __launch_bounds__(256)
void conv_silu_kernel(const float* __restrict__ xz,
                      const float* __restrict__ cw,
                      const float* __restrict__ cb,
                      float* __restrict__ xc, int rev)
{
    int idx = blockIdx.x * 256 + threadIdx.x;
    if (idx >= NTOK * D_INNER) return;
    int c   = idx & (D_INNER - 1);
    int row = idx >> 10;
    int b   = row / SEQ;
    int u   = row - b * SEQ;

    float w0 = cw[c * 4 + 0], w1 = cw[c * 4 + 1];
    float w2 = cw[c * 4 + 2], w3 = cw[c * 4 + 3];
    float accv = cb[c];
    if (!rev) {
#pragma unroll
        for (int k = 0; k < 4; ++k) {
            int uu = u - 3 + k;
            float wv = (k == 0) ? w0 : (k == 1) ? w1 : (k == 2) ? w2 : w3;
            if (uu >= 0)
                accv = fmaf(wv, xz[(b * SEQ + uu) * (2 * D_INNER) + c], accv);
        }
    } else {
#pragma unroll
        for (int k = 0; k < 4; ++k) {
            int uu = u + 3 - k;
            float wv = (k == 0) ? w0 : (k == 1) ? w1 : (k == 2) ? w2 : w3;
            if (uu < SEQ)
                accv = fmaf(wv, xz[(b * SEQ + uu) * (2 * D_INNER) + c], accv);
        }
    }
    xc[idx] = accv / (1.f + expf(-accv));
}

// ---------------- dt bias + softplus (in place) --------------------------
__global__ __launch_bounds__(256)
void bias_softplus_kernel(float* __restrict__ dt, const float* __restrict__ dtb)
{
    int idx = blockIdx.x * 256 + threadIdx.x;
    if (idx >= NTOK * D_INNER) return;
    int c = idx & (D_INNER - 1);
    float v = dt[idx] + dtb[c];
    dt[idx] = (v > 20.f) ? v : log1pf(expf(v));
}

// ---------------- chunked SSM scan ---------------------------------------
// Decomposition: h[t] = (prod da) * h_chunk_start + local_scan.
// Pass 1: per chunk, local scan from 0 -> (P, hE). Pass 2: 16-step scan over
// chunk summaries -> hstart per chunk. Pass 3: rerun local scan seeded with
// hstart, emit y.
// lane layout: s = tid&15 (state), cl = tid>>4 (channel within 16-chan group)
// summary layout: [(b*NCH + ch)*64 + cblk]*256 + cl*16 + s

__global__ __launch_bounds__(256)
void scan_chunk1(const float* __restrict__ dt,
                 const float* __restrict__ xc,
                 const float* __restrict__ xdbl,
                 const float* __restrict__ A_log,
                 float* __restrict__ chP,
                 float* __restrict__ chH, int rev)
{
    const int tid = threadIdx.x;
    const int s  = tid & 15;
    const int cl = tid >> 4;
    int blk = blockIdx.x;
    const int cblk = blk & 63;
    const int ch   = (blk >> 6) & (NCH - 1);
    const int b    = blk >> 10;
    const int c = cblk * 16 + cl;

    const float Acs = -expf(A_log[c * 16 + s]);
    float h = 0.f, P = 1.f;
#pragma unroll 4
    for (int i = 0; i < CHUNK; ++i) {
        int t = ch * CHUNK + i;
        int u = rev ? (SEQ - 1 - t) : t;
        int row = b * SEQ + u;
        float dtv = dt[row * D_INNER + c];
        float xcv = xc[row * D_INNER + c];
        float Bv  = xdbl[row * 64 + 32 + s];
        float da  = __expf(dtv * Acs);
        h = fmaf(da, h, dtv * xcv * Bv);
        P *= da;
    }
    int o = ((b * NCH + ch) * 64 + cblk) * 256 + cl * 16 + s;
    chP[o] = P;
    chH[o] = h;
}

__global__ __launch_bounds__(256)
void scan_chunk2(const float* __restrict__ chP,
                 const float* __restrict__ chH,
                 float* __restrict__ hstart)
{
    // one thread per (b, cblk, cl, s): B_SZ*64*256 = 32768 threads
    int idx = blockIdx.x * 256 + threadIdx.x;
    int b    = idx >> 14;
    int rest = idx & 16383;
    float h = 0.f;
#pragma unroll
    for (int ch = 0; ch < NCH; ++ch) {
        int o = ((b * NCH + ch) * 64) * 256 + rest;
        hstart[o] = h;
        h = fmaf(chP[o], h, chH[o]);
    }
}

__global__ __launch_bounds__(256)
void scan_chunk3(const float* __restrict__ dt,
                 const float* __restrict__ xc,
                 const float* __restrict__ xz,
                 const float* __restrict__ xdbl,
                 const float* __restrict__ A_log,
                 const float* __restrict__ Dp,
                 const float* __restrict__ hstart,
                 float* __restrict__ ybar, int rev)
{
    const int tid = threadIdx.x;
    const int s  = tid & 15;
    const int cl = tid >> 4;
    int blk = blockIdx.x;
    const int cblk = blk & 63;
    const int ch   = (blk >> 6) & (NCH - 1);
    const int b    = blk >> 10;
    const int c = cblk * 16 + cl;

    const float Acs = -expf(A_log[c * 16 + s]);
    const float Dc  = Dp[c];

    int o = ((b * NCH + ch) * 64 + cblk) * 256 + cl * 16 + s;
    float h = hstart[o];

#pragma unroll 4
    for (int i = 0; i < CHUNK; ++i) {
        int t = ch * CHUNK + i;
        int u = rev ? (SEQ - 1 - t) : t;
        int row = b * SEQ + u;
        float dtv = dt[row * D_INNER + c];
        float xcv = xc[row * D_INNER + c];
        float Bv  = xdbl[row * 64 + 32 + s];
        float Cv  = xdbl[row * 64 + 48 + s];
        float da  = __expf(dtv * Acs);
        h = fmaf(da, h, dtv * xcv * Bv);
        float p = h * Cv;
        p += __shfl_xor(p, 1);
        p += __shfl_xor(p, 2);
        p += __shfl_xor(p, 4);
        p += __shfl_xor(p, 8);
        if (s == 0) {
            float zv = xz[row * (2 * D_INNER) + D_INNER + c];
            float y  = p + Dc * xcv;
            ybar[row * D_INNER + c] = y * (zv / (1.f + expf(-zv)));
        }
    }
}

extern "C" void kernel_launch(void* const* d_in, const int* in_sizes, int n_in,
                              void* d_out, int out_size, void* d_ws, size_t ws_size,
                              hipStream_t stream)
{
    const float* x = (const float*)d_in[0];
    float* out = (float*)d_out;
    float* ws  = (float*)d_ws;

    // workspace layout (floats), reused across directions:
    float* xz   = ws;                                   // NTOK*2048
    float* xc   = xz   + (size_t)NTOK * 2 * D_INNER;    // NTOK*1024
    float* xdbl = xc   + (size_t)NTOK * D_INNER;        // NTOK*64
    float* dt   = xdbl + (size_t)NTOK * 64;             // NTOK*1024
    float* ybar = dt   + (size_t)NTOK * D_INNER;        // NTOK*1024
    float* chP  = ybar + (size_t)NTOK * D_INNER;        // B*NCH*64*256
    float* chH  = chP  + (size_t)B_SZ * NCH * 64 * 256;
    float* hst  = chH  + (size_t)B_SZ * NCH * 64 * 256;

    const int elemN = NTOK * D_INNER;
    const int gElem = (elemN + 255) / 256;
    const int gScan = B_SZ * NCH * 64;   // 2048 blocks

    for (int dir = 0; dir < 2; ++dir) {
        const float* in_w    = (const float*)d_in[1 + dir * 9 + 0];
        const float* conv_w  = (const float*)d_in[1 + dir * 9 + 1];
        const float* conv_b  = (const float*)d_in[1 + dir * 9 + 2];
        const float* xproj_w = (const float*)d_in[1 + dir * 9 + 3];
        const float* dt_w    = (const float*)d_in[1 + dir * 9 + 4];
        const float* dt_b    = (const float*)d_in[1 + dir * 9 + 5];
        const float* A_log   = (const float*)d_in[1 + dir * 9 + 6];
        const float* Dp      = (const float*)d_in[1 + dir * 9 + 7];
        const float* out_w   = (const float*)d_in[1 + dir * 9 + 8];

        // 1) xz = x @ in_w.T   [4096, 2048]
        {
            dim3 g(2 * D_INNER / GBN, NTOK / GBM);
            gemm_xwT<<<g, 256, 0, stream>>>(x, DIM, in_w, DIM,
                                            xz, 2 * D_INNER,
                                            NTOK, 2 * D_INNER, DIM, 1.f, 0);
        }
        // 2) conv + silu -> xc
        conv_silu_kernel<<<gElem, 256, 0, stream>>>(xz, conv_w, conv_b, xc, dir);
        // 3) x_dbl = xc @ xproj_w.T   [4096, 64]
        {
            dim3 g(64 / GBN, NTOK / GBM);
            gemm_xwT<<<g, 256, 0, stream>>>(xc, D_INNER, xproj_w, D_INNER,
                                            xdbl, 64,
                                            NTOK, 64, D_INNER, 1.f, 0);
        }
        // 4) dt_pre = x_dbl[:, :32] @ dt_w.T   [4096, 1024]
        {
            dim3 g(D_INNER / GBN, NTOK / GBM);
            gemm_xwT<<<g, 256, 0, stream>>>(xdbl, 64, dt_w, DT_RANK,
                                            dt, D_INNER,
                                            NTOK, D_INNER, DT_RANK, 1.f, 0);
        }
        // 5) dt = softplus(dt_pre + dt_b)
        bias_softplus_kernel<<<gElem, 256, 0, stream>>>(dt, dt_b);
        // 6) chunked scan -> ybar
        scan_chunk1<<<gScan, 256, 0, stream>>>(dt, xc, xdbl, A_log, chP, chH, dir);
        scan_chunk2<<<(B_SZ * 64 * 256) / 256, 256, 0, stream>>>(chP, chH, hst);
        scan_chunk3<<<gScan, 256, 0, stream>>>(dt, xc, xz, xdbl, A_log, Dp,
                                               hst, ybar, dir);
        // 7) out (+)= 0.5 * ybar @ out_w.T   [4096, 512]
        {
            dim3 g(DIM / GBN, NTOK / GBM);
            gemm_xwT<<<g, 256, 0, stream>>>(ybar, D_INNER, out_w, D_INNER,
                                            out, DIM,
                                            NTOK, DIM, D_INNER, 0.5f, dir);
        }
    }
}

// Round 4
// 705.486 us; speedup vs baseline: 5.2356x; 1.2459x over previous
//
#include <hip/hip_runtime.h>
#include <hip/hip_bf16.h>
#include <math.h>

#define DIM      512
#define D_STATE  16
#define D_CONV   4
#define D_INNER  1024
#define DT_RANK  32
#define B_SZ     2
#define SEQ      2048
#define NTOK     (B_SZ * SEQ)   // 4096
#define CHUNK    128
#define NCH      (SEQ / CHUNK)  // 16
#define NC_PAD   1152           // 1024 dt + 32 BC + 96 pad

typedef __attribute__((ext_vector_type(8))) short bf16x8;
typedef __attribute__((ext_vector_type(4))) float f32x4;

__device__ __forceinline__ short f2bf(float f) {
    unsigned u = __float_as_uint(f);
    u += 0x7fffu + ((u >> 16) & 1u);
    return (short)(u >> 16);
}

// ---------------- MFMA GEMM: C[M,N] (+)= alpha * A[M,K] @ W[N,K]^T ----------
// fp32 global operands, converted to bf16 during staging. 128x128 tile,
// BK=32, 256 thr = 4 waves (2x2), wave tile 64x64 (4x4 frags of 16x16x32).
// LDS layout: 16B chunk index = mblk*64 + kc*16 + mlocal  (m = mblk*16+mlocal,
// k = kc*8..+8) -> both staging writes and fragment reads are lane-contiguous.
#define TM 128
#define TN 128
#define TK 32

__global__ __launch_bounds__(256)
void gemm_mfma(const float* __restrict__ A, int lda,
               const float* __restrict__ W, int ldw,
               float* __restrict__ C, int ldc,
               int K, float alpha, int accum)
{
    __shared__ __align__(16) short As[TM * TK];
    __shared__ __align__(16) short Ws[TN * TK];

    const int tid  = threadIdx.x;
    const int lane = tid & 63;
    const int wid  = tid >> 6;
    const int wr   = wid >> 1, wc = wid & 1;
    const int m0 = blockIdx.y * TM;
    const int n0 = blockIdx.x * TN;

    // staging chunks: tid and tid+256 (chunk ci -> m=(ci>>6)*16+(ci&15), kc=(ci>>4)&3)
    const int ci0 = tid, ci1 = tid + 256;
    const int am0 = ((ci0 >> 6) << 4) | (ci0 & 15), kc0 = (ci0 >> 4) & 3;
    const int am1 = ((ci1 >> 6) << 4) | (ci1 & 15), kc1 = (ci1 >> 4) & 3;

    const float* pa0 = A + (size_t)(m0 + am0) * lda + kc0 * 8;
    const float* pa1 = A + (size_t)(m0 + am1) * lda + kc1 * 8;
    const float* pw0 = W + (size_t)(n0 + am0) * ldw + kc0 * 8;
    const float* pw1 = W + (size_t)(n0 + am1) * ldw + kc1 * 8;

    f32x4 acc[4][4] = {};

    for (int k0 = 0; k0 < K; k0 += TK) {
#pragma unroll
        for (int q = 0; q < 4; ++q) {
            const float* src = (q == 0) ? pa0 + k0 : (q == 1) ? pa1 + k0
                             : (q == 2) ? pw0 + k0 : pw1 + k0;
            short* dst = (q < 2) ? As : Ws;
            int ci = (q & 1) ? ci1 : ci0;
            float4 a = *(const float4*)(src);
            float4 b = *(const float4*)(src + 4);
            bf16x8 v;
            v[0] = f2bf(a.x); v[1] = f2bf(a.y); v[2] = f2bf(a.z); v[3] = f2bf(a.w);
            v[4] = f2bf(b.x); v[5] = f2bf(b.y); v[6] = f2bf(b.z); v[7] = f2bf(b.w);
            *(bf16x8*)(dst + ci * 8) = v;
        }
        __syncthreads();

        bf16x8 af[4], bff[4];
#pragma unroll
        for (int f = 0; f < 4; ++f) {
            int ai = (wr * 4 + f) * 64 + (lane >> 4) * 16 + (lane & 15);
            af[f]  = *(const bf16x8*)(As + ai * 8);
            int bi = (wc * 4 + f) * 64 + (lane >> 4) * 16 + (lane & 15);
            bff[f] = *(const bf16x8*)(Ws + bi * 8);
        }
#pragma unroll
        for (int i = 0; i < 4; ++i)
#pragma unroll
            for (int j = 0; j < 4; ++j)
                acc[i][j] = __builtin_amdgcn_mfma_f32_16x16x32_bf16(
                    af[i], bff[j], acc[i][j], 0, 0, 0);
        __syncthreads();
    }

#pragma unroll
    for (int i = 0; i < 4; ++i) {
        int row = m0 + wr * 64 + i * 16 + ((lane >> 4) << 2);
#pragma unroll
        for (int j = 0; j < 4; ++j) {
            int col = n0 + wc * 64 + j * 16 + (lane & 15);
#pragma unroll
            for (int r = 0; r < 4; ++r) {
                float v = alpha * acc[i][j][r];
                float* p = &C[(size_t)(row + r) * ldc + col];
                if (accum) *p += v; else *p = v;
            }
        }
    }
}

// ---------------- combined projection weight -----------------------------
// Wc[1152,1024]: rows 0..1023 = dt_w @ xproj_w[:32,:]; rows 1024..1055 =
// xproj_w[32..63,:] (B then C); rows 1056.. = 0.
__global__ __launch_bounds__(256)
void build_wc(const float* __restrict__ xproj_w,  // [64,1024]
              const float* __restrict__ dt_w,     // [1024,32]
              float* __restrict__ Wc)             // [1152,1024]
{
    int idx = blockIdx.x * 256 + threadIdx.x;
    if (idx >= NC_PAD * D_INNER) return;
    int i = idx >> 10, k = idx & 1023;
    float v;
    if (i < 1024) {
        v = 0.f;
#pragma unroll
        for (int r = 0; r < 32; ++r)
            v = fmaf(dt_w[i * 32 + r], xproj_w[r * 1024 + k], v);
    } else if (i < 1056) {
        v = xproj_w[(i - 1024 + 32) * 1024 + k];
    } else {
        v = 0.f;
    }
    Wc[idx] = v;
}

// ---------------- depthwise causal conv (k=4) + bias + SiLU --------------
__global__ __launch_bounds__(256)
void conv_silu_kernel(const float* __restrict__ xz,
                      const float* __restrict__ cw,
                      const float* __restrict__ cb,
                      float* __restrict__ xc, int rev)
{
    int idx = blockIdx.x * 256 + threadIdx.x;
    if (idx >= NTOK * D_INNER) return;
    int c   = idx & (D_INNER - 1);
    int row = idx >> 10;
    int b   = row / SEQ;
    int u   = row - b * SEQ;

    float w0 = cw[c * 4 + 0], w1 = cw[c * 4 + 1];
    float w2 = cw[c * 4 + 2], w3 = cw[c * 4 + 3];
    float accv = cb[c];
    if (!rev) {
#pragma unroll
        for (int k = 0; k < 4; ++k) {
            int uu = u - 3 + k;
            float wv = (k == 0) ? w0 : (k == 1) ? w1 : (k == 2) ? w2 : w3;
            if (uu >= 0)
                accv = fmaf(wv, xz[(size_t)(b * SEQ + uu) * (2 * D_INNER) + c], accv);
        }
    } else {
#pragma unroll
        for (int k = 0; k < 4; ++k) {
            int uu = u + 3 - k;
            float wv = (k == 0) ? w0 : (k == 1) ? w1 : (k == 2) ? w2 : w3;
            if (uu < SEQ)
                accv = fmaf(wv, xz[(size_t)(b * SEQ + uu) * (2 * D_INNER) + c], accv);
        }
    }
    xc[idx] = accv / (1.f + expf(-accv));
}

// ---------------- dt bias + softplus (in place, strided) -----------------
__global__ __launch_bounds__(256)
void bias_softplus_kernel(float* __restrict__ xdblP, const float* __restrict__ dtb)
{
    int idx = blockIdx.x * 256 + threadIdx.x;
    if (idx >= NTOK * D_INNER) return;
    int c = idx & (D_INNER - 1);
    int row = idx >> 10;
    float* p = &xdblP[(size_t)row * NC_PAD + c];
    float v = *p + dtb[c];
    *p = (v > 20.f) ? v : log1pf(expf(v));
}

// ---------------- chunked SSM scan ---------------------------------------
// xdblP row layout: [0..1023]=dt (post-softplus), [1024..1039]=B, [1040..1055]=C
__global__ __launch_bounds__(256)
void scan_chunk1(const float* __restrict__ xdblP,
                 const float* __restrict__ xc,
                 const float* __restrict__ A_log,
                 float* __restrict__ chP,
                 float* __restrict__ chH, int rev)
{
    const int tid = threadIdx.x;
    const int s  = tid & 15;
    const int cl = tid >> 4;
    int blk = blockIdx.x;
    const int cblk = blk & 63;
    const int ch   = (blk >> 6) & (NCH - 1);
    const int b    = blk >> 10;
    const int c = cblk * 16 + cl;

    const float Acs = -expf(A_log[c * 16 + s]);
    float h = 0.f, P = 1.f;
#pragma unroll 4
    for (int i = 0; i < CHUNK; ++i) {
        int t = ch * CHUNK + i;
        int u = rev ? (SEQ - 1 - t) : t;
        int row = b * SEQ + u;
        float dtv = xdblP[(size_t)row * NC_PAD + c];
        float xcv = xc[(size_t)row * D_INNER + c];
        float Bv  = xdblP[(size_t)row * NC_PAD + 1024 + s];
        float da  = __expf(dtv * Acs);
        h = fmaf(da, h, dtv * xcv * Bv);
        P *= da;
    }
    int o = ((b * NCH + ch) * 64 + cblk) * 256 + cl * 16 + s;
    chP[o] = P;
    chH[o] = h;
}

__global__ __launch_bounds__(256)
void scan_chunk2(const float* __restrict__ chP,
                 const float* __restrict__ chH,
                 float* __restrict__ hstart)
{
    int idx = blockIdx.x * 256 + threadIdx.x;
    int b    = idx >> 14;
    int rest = idx & 16383;
    float h = 0.f;
#pragma unroll
    for (int ch = 0; ch < NCH; ++ch) {
        int o = ((b * NCH + ch) * 64) * 256 + rest;
        hstart[o] = h;
        h = fmaf(chP[o], h, chH[o]);
    }
}

__global__ __launch_bounds__(256)
void scan_chunk3(const float* __restrict__ xdblP,
                 const float* __restrict__ xc,
                 const float* __restrict__ xz,
                 const float* __restrict__ A_log,
                 const float* __restrict__ Dp,
                 const float* __restrict__ hstart,
                 float* __restrict__ ybar, int rev)
{
    const int tid = threadIdx.x;
    const int s  = tid & 15;
    const int cl = tid >> 4;
    int blk = blockIdx.x;
    const int cblk = blk & 63;
    const int ch   = (blk >> 6) & (NCH - 1);
    const int b    = blk >> 10;
    const int c = cblk * 16 + cl;

    const float Acs = -expf(A_log[c * 16 + s]);
    const float Dc  = Dp[c];

    int o = ((b * NCH + ch) * 64 + cblk) * 256 + cl * 16 + s;
    float h = hstart[o];

#pragma unroll 4
    for (int i = 0; i < CHUNK; ++i) {
        int t = ch * CHUNK + i;
        int u = rev ? (SEQ - 1 - t) : t;
        int row = b * SEQ + u;
        float dtv = xdblP[(size_t)row * NC_PAD + c];
        float xcv = xc[(size_t)row * D_INNER + c];
        float Bv  = xdblP[(size_t)row * NC_PAD + 1024 + s];
        float Cv  = xdblP[(size_t)row * NC_PAD + 1040 + s];
        float da  = __expf(dtv * Acs);
        h = fmaf(da, h, dtv * xcv * Bv);
        float p = h * Cv;
        p += __shfl_xor(p, 1);
        p += __shfl_xor(p, 2);
        p += __shfl_xor(p, 4);
        p += __shfl_xor(p, 8);
        if (s == 0) {
            float zv = xz[(size_t)row * (2 * D_INNER) + D_INNER + c];
            float y  = p + Dc * xcv;
            ybar[(size_t)row * D_INNER + c] = y * (zv / (1.f + expf(-zv)));
        }
    }
}

extern "C" void kernel_launch(void* const* d_in, const int* in_sizes, int n_in,
                              void* d_out, int out_size, void* d_ws, size_t ws_size,
                              hipStream_t stream)
{
    const float* x = (const float*)d_in[0];
    float* out = (float*)d_out;
    float* ws  = (float*)d_ws;

    // workspace layout (floats), reused across directions:
    float* xz    = ws;                                    // NTOK*2048
    float* xc    = xz    + (size_t)NTOK * 2 * D_INNER;    // NTOK*1024
    float* xdblP = xc    + (size_t)NTOK * D_INNER;        // NTOK*1152
    float* ybar  = xdblP + (size_t)NTOK * NC_PAD;         // NTOK*1024
    float* chP   = ybar  + (size_t)NTOK * D_INNER;        // 524288
    float* chH   = chP   + (size_t)B_SZ * NCH * 64 * 256;
    float* hst   = chH   + (size_t)B_SZ * NCH * 64 * 256;
    float* Wc    = chP;  // alias: Wc consumed before scan writes chP/chH/hst

    const int elemN = NTOK * D_INNER;
    const int gElem = (elemN + 255) / 256;
    const int gScan = B_SZ * NCH * 64;   // 2048 blocks

    for (int dir = 0; dir < 2; ++dir) {
        const float* in_w    = (const float*)d_in[1 + dir * 9 + 0];
        const float* conv_w  = (const float*)d_in[1 + dir * 9 + 1];
        const float* conv_b  = (const float*)d_in[1 + dir * 9 + 2];
        const float* xproj_w = (const float*)d_in[1 + dir * 9 + 3];
        const float* dt_w    = (const float*)d_in[1 + dir * 9 + 4];
        const float* dt_b    = (const float*)d_in[1 + dir * 9 + 5];
        const float* A_log   = (const float*)d_in[1 + dir * 9 + 6];
        const float* Dp      = (const float*)d_in[1 + dir * 9 + 7];
        const float* out_w   = (const float*)d_in[1 + dir * 9 + 8];

        // 0) combined projection weight Wc = [dt_w @ xproj_w[:32]; xproj_w[32:64]; 0]
        build_wc<<<(NC_PAD * D_INNER + 255) / 256, 256, 0, stream>>>(
            xproj_w, dt_w, Wc);

        // 1) xz = x @ in_w.T   [4096, 2048]
        {
            dim3 g(2 * D_INNER / TN, NTOK / TM);
            gemm_mfma<<<g, 256, 0, stream>>>(x, DIM, in_w, DIM,
                                             xz, 2 * D_INNER, DIM, 1.f, 0);
        }
        // 2) conv + silu -> xc
        conv_silu_kernel<<<gElem, 256, 0, stream>>>(xz, conv_w, conv_b, xc, dir);
        // 3+4) xdblP = xc @ Wc.T  [4096, 1152]  (dt_pre | B | C | pad)
        {
            dim3 g(NC_PAD / TN, NTOK / TM);
            gemm_mfma<<<g, 256, 0, stream>>>(xc, D_INNER, Wc, D_INNER,
                                             xdblP, NC_PAD, D_INNER, 1.f, 0);
        }
        // 5) dt = softplus(dt_pre + dt_b)  (in place, cols 0..1023)
        bias_softplus_kernel<<<gElem, 256, 0, stream>>>(xdblP, dt_b);
        // 6) chunked scan -> ybar
        scan_chunk1<<<gScan, 256, 0, stream>>>(xdblP, xc, A_log, chP, chH, dir);
        scan_chunk2<<<(B_SZ * 64 * 256) / 256, 256, 0, stream>>>(chP, chH, hst);
        scan_chunk3<<<gScan, 256, 0, stream>>>(xdblP, xc, xz, A_log, Dp,
                                               hst, ybar, dir);
        // 7) out (+)= 0.5 * ybar @ out_w.T   [4096, 512]
        {
            dim3 g(DIM / TN, NTOK / TM);
            gemm_mfma<<<g, 256, 0, stream>>>(ybar, D_INNER, out_w, D_INNER,
                                             out, DIM, D_INNER, 0.5f, dir);
        }
    }
}